// Round 1
// baseline (1143.661 us; speedup 1.0000x reference)
//
#include <hip/hip_runtime.h>

#define Bc 16
#define Tc 16
#define Cc 512
#define Kc 64
#define Hc 14
#define Sc 196
#define NTc 256
#define BKS (Bc*Kc*Sc)      // 200704
#define TBKS (Tc*BKS)       // 3211264

__device__ __forceinline__ float sigmoid_f(float x) { return 1.f / (1.f + __expf(-x)); }
__device__ __forceinline__ float tanh_f(float x) { return 1.f - 2.f / (__expf(2.f * x) + 1.f); }

// ---------------- transpose share_w: wt[c][k] = w[k][c] ----------------
__global__ __launch_bounds__(256) void k_transpose_w(const float* __restrict__ w, float* __restrict__ wt) {
    int idx = blockIdx.x * 256 + threadIdx.x;
    if (idx < Kc * Cc) {
        int k = idx & 63, c = idx >> 6;
        wt[idx] = w[k * Cc + c];
    }
}

// ---------------- conv1x1: wxb[t][b][k][s] = sum_c W[k][c] X[n][c][s] + bias[k] ----------------
// flat gs = n*196+s tiling: grid 784 blocks x 64 gs, full K in registers loop.
__global__ __launch_bounds__(256) void k_conv1x1(const float* __restrict__ x, const float* __restrict__ wt,
                                                 const float* __restrict__ bias, float* __restrict__ wxb) {
    __shared__ float Ws[32][64];
    __shared__ float Xs[32][64];
    const int tid = threadIdx.x;
    const int gs0 = blockIdx.x * 64;
    const int kt = tid >> 4;          // 0..15 -> k base kt*4
    const int sg = tid & 15;          // 0..15 -> col base sg*4
    const int sr = tid >> 3;          // staging row 0..31
    const int scol0 = (tid & 7) * 8;  // staging col base

    int nj[8], sj[8];
#pragma unroll
    for (int j = 0; j < 8; ++j) {
        int gs = gs0 + scol0 + j;
        nj[j] = gs / Sc;
        sj[j] = gs - nj[j] * Sc;
    }
    float acc[4][4] = {};
    for (int c0 = 0; c0 < Cc; c0 += 32) {
        __syncthreads();
        {
            const float* wp = wt + (size_t)(c0 + sr) * Kc + scol0;
            float4 a = *(const float4*)wp;
            float4 b = *(const float4*)(wp + 4);
            *(float4*)&Ws[sr][scol0] = a;
            *(float4*)&Ws[sr][scol0 + 4] = b;
        }
#pragma unroll
        for (int j = 0; j < 8; ++j) {
            Xs[sr][scol0 + j] = x[((size_t)nj[j] * Cc + c0 + sr) * Sc + sj[j]];
        }
        __syncthreads();
#pragma unroll
        for (int cc = 0; cc < 32; ++cc) {
            float4 wv = *(const float4*)&Ws[cc][kt * 4];
            float4 xv = *(const float4*)&Xs[cc][sg * 4];
            acc[0][0] += wv.x * xv.x; acc[0][1] += wv.x * xv.y; acc[0][2] += wv.x * xv.z; acc[0][3] += wv.x * xv.w;
            acc[1][0] += wv.y * xv.x; acc[1][1] += wv.y * xv.y; acc[1][2] += wv.y * xv.z; acc[1][3] += wv.y * xv.w;
            acc[2][0] += wv.z * xv.x; acc[2][1] += wv.z * xv.y; acc[2][2] += wv.z * xv.z; acc[2][3] += wv.z * xv.w;
            acc[3][0] += wv.w * xv.x; acc[3][1] += wv.w * xv.y; acc[3][2] += wv.w * xv.z; acc[3][3] += wv.w * xv.w;
        }
    }
#pragma unroll
    for (int i = 0; i < 4; ++i) {
        int k = kt * 4 + i;
        float bv = bias[k];
#pragma unroll
        for (int j = 0; j < 4; ++j) {
            int gs = gs0 + sg * 4 + j;
            int n = gs / Sc, s = gs - (gs / Sc) * Sc;
            int t = n & 15, b = n >> 4;
            wxb[(((size_t)t * Bc + b) * Kc + k) * Sc + s] = acc[i][j] + bv;
        }
    }
}

// ---------------- GRU gates: z = sig(wxb + conv(h,Uz)), r = sig(wxb + conv(h,Ur)); store z, r*h ----------------
// grid (16 ktiles, 16 b), block 256 (4 waves = 4 k_out). Pixel-pair per lane.
__global__ __launch_bounds__(256) void k_gru_gates(const float* __restrict__ hprev,
        const float* __restrict__ wxb_t, const float* __restrict__ Uz, const float* __restrict__ Ur,
        float* __restrict__ zb, float* __restrict__ rh) {
    __shared__ float hs[Kc][Hc][20];
    const int b = blockIdx.y;
    const int k0 = blockIdx.x * 4;
    const int tid = threadIdx.x;
    for (int i = tid; i < Kc * Hc; i += 256) {
        int kk = i / Hc, y = i - kk * Hc;
        hs[kk][y][0] = 0.f; hs[kk][y][15] = 0.f;
    }
    {
        const float* hb = hprev + (size_t)b * Kc * Sc;
        for (int i = tid; i < Kc * Sc; i += 256) {
            int kk = i / Sc, s = i - kk * Sc;
            int y = s / 14, xx = s - y * 14;
            hs[kk][y][xx + 1] = hb[i];
        }
    }
    __syncthreads();
    const int wave = tid >> 6, lane = tid & 63;
    const int k = __builtin_amdgcn_readfirstlane(k0 + wave);
    const float* uzp = Uz + (size_t)k * (Kc * 9);
    const float* urp = Ur + (size_t)k * (Kc * 9);
    float az[2][2] = {{0.f,0.f},{0.f,0.f}}, ar[2][2] = {{0.f,0.f},{0.f,0.f}};
    const int p0 = lane, p1 = lane + 64;
    const int y0 = p0 / 7, x0 = (p0 - y0 * 7) * 2;
    const int y1 = p1 / 7, x1 = (p1 - y1 * 7) * 2;
    const bool v1 = (p1 < 98);
    for (int ki = 0; ki < Kc; ++ki) {
        float uz[9], ur[9];
#pragma unroll
        for (int q = 0; q < 9; ++q) { uz[q] = uzp[ki * 9 + q]; ur[q] = urp[ki * 9 + q]; }
#pragma unroll
        for (int dy = 0; dy < 3; ++dy) {
            int yy = y0 + dy - 1;
            if ((unsigned)yy < 14u) {
                const float* row = &hs[ki][yy][x0];
                float2 a = *(const float2*)row;
                float2 c = *(const float2*)(row + 2);
                az[0][0] += a.x*uz[3*dy] + a.y*uz[3*dy+1] + c.x*uz[3*dy+2];
                az[0][1] += a.y*uz[3*dy] + c.x*uz[3*dy+1] + c.y*uz[3*dy+2];
                ar[0][0] += a.x*ur[3*dy] + a.y*ur[3*dy+1] + c.x*ur[3*dy+2];
                ar[0][1] += a.y*ur[3*dy] + c.x*ur[3*dy+1] + c.y*ur[3*dy+2];
            }
        }
        if (v1) {
#pragma unroll
            for (int dy = 0; dy < 3; ++dy) {
                int yy = y1 + dy - 1;
                if ((unsigned)yy < 14u) {
                    const float* row = &hs[ki][yy][x1];
                    float2 a = *(const float2*)row;
                    float2 c = *(const float2*)(row + 2);
                    az[1][0] += a.x*uz[3*dy] + a.y*uz[3*dy+1] + c.x*uz[3*dy+2];
                    az[1][1] += a.y*uz[3*dy] + c.x*uz[3*dy+1] + c.y*uz[3*dy+2];
                    ar[1][0] += a.x*ur[3*dy] + a.y*ur[3*dy+1] + c.x*ur[3*dy+2];
                    ar[1][1] += a.y*ur[3*dy] + c.x*ur[3*dy+1] + c.y*ur[3*dy+2];
                }
            }
        }
    }
    const float2* wx2 = (const float2*)(wxb_t + ((size_t)b * Kc + k) * Sc);
    float2* zb2 = (float2*)(zb + ((size_t)b * Kc + k) * Sc);
    float2* rh2 = (float2*)(rh + ((size_t)b * Kc + k) * Sc);
    {
        float2 pre = wx2[p0];
        float z0 = sigmoid_f(pre.x + az[0][0]);
        float z1 = sigmoid_f(pre.y + az[0][1]);
        float r0 = sigmoid_f(pre.x + ar[0][0]);
        float r1 = sigmoid_f(pre.y + ar[0][1]);
        float h0v = hs[k][y0][x0 + 1];
        float h1v = hs[k][y0][x0 + 2];
        zb2[p0] = make_float2(z0, z1);
        rh2[p0] = make_float2(r0 * h0v, r1 * h1v);
    }
    if (v1) {
        float2 pre = wx2[p1];
        float z0 = sigmoid_f(pre.x + az[1][0]);
        float z1 = sigmoid_f(pre.y + az[1][1]);
        float r0 = sigmoid_f(pre.x + ar[1][0]);
        float r1 = sigmoid_f(pre.y + ar[1][1]);
        float h0v = hs[k][y1][x1 + 1];
        float h1v = hs[k][y1][x1 + 2];
        zb2[p1] = make_float2(z0, z1);
        rh2[p1] = make_float2(r0 * h0v, r1 * h1v);
    }
}

// ---------------- GRU out: hh = tanh(wxb + conv(rh,Uh)); h = (1-z)*hh + z*hprev ----------------
__global__ __launch_bounds__(256) void k_gru_out(const float* __restrict__ rhin, const float* __restrict__ hprev,
        const float* __restrict__ wxb_t, const float* __restrict__ Uh, const float* __restrict__ zb,
        float* __restrict__ hout) {
    __shared__ float hs[Kc][Hc][20];
    const int b = blockIdx.y;
    const int k0 = blockIdx.x * 4;
    const int tid = threadIdx.x;
    for (int i = tid; i < Kc * Hc; i += 256) {
        int kk = i / Hc, y = i - kk * Hc;
        hs[kk][y][0] = 0.f; hs[kk][y][15] = 0.f;
    }
    {
        const float* hb = rhin + (size_t)b * Kc * Sc;
        for (int i = tid; i < Kc * Sc; i += 256) {
            int kk = i / Sc, s = i - kk * Sc;
            int y = s / 14, xx = s - y * 14;
            hs[kk][y][xx + 1] = hb[i];
        }
    }
    __syncthreads();
    const int wave = tid >> 6, lane = tid & 63;
    const int k = __builtin_amdgcn_readfirstlane(k0 + wave);
    const float* uhp = Uh + (size_t)k * (Kc * 9);
    float ah[2][2] = {{0.f,0.f},{0.f,0.f}};
    const int p0 = lane, p1 = lane + 64;
    const int y0 = p0 / 7, x0 = (p0 - y0 * 7) * 2;
    const int y1 = p1 / 7, x1 = (p1 - y1 * 7) * 2;
    const bool v1 = (p1 < 98);
    for (int ki = 0; ki < Kc; ++ki) {
        float uh[9];
#pragma unroll
        for (int q = 0; q < 9; ++q) uh[q] = uhp[ki * 9 + q];
#pragma unroll
        for (int dy = 0; dy < 3; ++dy) {
            int yy = y0 + dy - 1;
            if ((unsigned)yy < 14u) {
                const float* row = &hs[ki][yy][x0];
                float2 a = *(const float2*)row;
                float2 c = *(const float2*)(row + 2);
                ah[0][0] += a.x*uh[3*dy] + a.y*uh[3*dy+1] + c.x*uh[3*dy+2];
                ah[0][1] += a.y*uh[3*dy] + c.x*uh[3*dy+1] + c.y*uh[3*dy+2];
            }
        }
        if (v1) {
#pragma unroll
            for (int dy = 0; dy < 3; ++dy) {
                int yy = y1 + dy - 1;
                if ((unsigned)yy < 14u) {
                    const float* row = &hs[ki][yy][x1];
                    float2 a = *(const float2*)row;
                    float2 c = *(const float2*)(row + 2);
                    ah[1][0] += a.x*uh[3*dy] + a.y*uh[3*dy+1] + c.x*uh[3*dy+2];
                    ah[1][1] += a.y*uh[3*dy] + c.x*uh[3*dy+1] + c.y*uh[3*dy+2];
                }
            }
        }
    }
    const size_t base = ((size_t)b * Kc + k) * Sc;
    const float2* wx2 = (const float2*)(wxb_t + base);
    const float2* zb2 = (const float2*)(zb + base);
    const float2* hp2 = (const float2*)(hprev + base);
    float2* ho2 = (float2*)(hout + base);
    {
        float2 pre = wx2[p0]; float2 zv = zb2[p0]; float2 hp = hp2[p0];
        float hh0 = tanh_f(pre.x + ah[0][0]);
        float hh1 = tanh_f(pre.y + ah[0][1]);
        ho2[p0] = make_float2((1.f - zv.x) * hh0 + zv.x * hp.x,
                              (1.f - zv.y) * hh1 + zv.y * hp.y);
    }
    if (v1) {
        float2 pre = wx2[p1]; float2 zv = zb2[p1]; float2 hp = hp2[p1];
        float hh0 = tanh_f(pre.x + ah[1][0]);
        float hh1 = tanh_f(pre.y + ah[1][1]);
        ho2[p1] = make_float2((1.f - zv.x) * hh0 + zv.x * hp.x,
                              (1.f - zv.y) * hh1 + zv.y * hp.y);
    }
}

// ---------------- asum_tot[b][k] = sum_{t,s} assign ----------------
__global__ __launch_bounds__(64) void k_asum(const float* __restrict__ assign, float* __restrict__ asum) {
    const int bk = blockIdx.x;
    const int b = bk >> 6, k = bk & 63;
    float s = 0.f;
    for (int i = threadIdx.x; i < Tc * Sc; i += 64) {
        int t = i / Sc, sp = i - t * Sc;
        s += assign[(((size_t)t * Bc + b) * Kc + k) * Sc + sp];
    }
#pragma unroll
    for (int o = 1; o < 64; o <<= 1) s += __shfl_xor(s, o);
    if (threadIdx.x == 0) asum[bk] = s;
}

// ---------------- einsum partials: part[g][b][k][c] = sum_{t in g, s} assign[t,b,k,s]*x[n,c,s] ----------------
__global__ __launch_bounds__(256) void k_einsum(const float* __restrict__ x, const float* __restrict__ assign,
                                                float* __restrict__ part) {
    __shared__ float As[Kc][200];
    __shared__ float Xs[128][29];
    const int ct = blockIdx.x, tg = blockIdx.y, b = blockIdx.z;
    const int tid = threadIdx.x;
    const int kt = tid >> 4;   // k = kt + 16*i
    const int cg = tid & 15;   // c = cg + 16*j
    float acc[4][8] = {};
    for (int ti = 0; ti < 4; ++ti) {
        const int t = tg * 4 + ti;
        const int n = b * Tc + t;
        __syncthreads();
        {
            const float* ap = assign + ((size_t)t * Bc + b) * Kc * Sc;
            for (int i = tid; i < Kc * Sc; i += 256) As[i / Sc][i - (i / Sc) * Sc] = ap[i];
        }
        for (int sc = 0; sc < 7; ++sc) {
            const int sb = sc * 28;
            __syncthreads();
            {
                const int r = tid >> 1, half = tid & 1;
                const float* xp = x + ((size_t)n * Cc + ct * 128 + r) * Sc + sb + half * 14;
                float* xd = &Xs[r][half * 14];
#pragma unroll
                for (int j = 0; j < 14; ++j) xd[j] = xp[j];
            }
            __syncthreads();
            for (int s = 0; s < 28; ++s) {
                float av[4], xv[8];
#pragma unroll
                for (int i = 0; i < 4; ++i) av[i] = As[kt + 16 * i][sb + s];
#pragma unroll
                for (int j = 0; j < 8; ++j) xv[j] = Xs[cg + 16 * j][s];
#pragma unroll
                for (int i = 0; i < 4; ++i)
#pragma unroll
                    for (int j = 0; j < 8; ++j) acc[i][j] += av[i] * xv[j];
            }
        }
    }
#pragma unroll
    for (int i = 0; i < 4; ++i) {
        int k = kt + 16 * i;
#pragma unroll
        for (int j = 0; j < 8; ++j) {
            int c = ct * 128 + cg + 16 * j;
            part[(((size_t)tg * Bc + b) * Kc + k) * Cc + c] = acc[i][j];
        }
    }
}

// ---------------- finalize: vlad = sum_g part - asum*centers; intra-norm over C; global norm; write ----------------
__global__ __launch_bounds__(256) void k_finalize(const float* __restrict__ part, const float* __restrict__ asum,
        const float* __restrict__ centers, float* __restrict__ out) {
    __shared__ float invk[Kc];
    __shared__ float wss[4];
    __shared__ float ginv_s;
    const int b = blockIdx.x;
    const int wave = threadIdx.x >> 6, lane = threadIdx.x & 63;
    const size_t G = (size_t)Bc * Kc * Cc;
    float gss = 0.f;
    for (int k = wave; k < Kc; k += 4) {
        const float a = asum[b * Kc + k];
        const float* pp = part + ((size_t)b * Kc + k) * Cc;
        const float* cp = centers + (size_t)k * Cc;
        float ss = 0.f;
#pragma unroll
        for (int cpass = 0; cpass < 8; ++cpass) {
            int c = cpass * 64 + lane;
            float v = pp[c] + pp[c + G] + pp[c + 2 * G] + pp[c + 3 * G] - a * cp[c];
            ss += v * v;
        }
#pragma unroll
        for (int o = 1; o < 64; o <<= 1) ss += __shfl_xor(ss, o);
        float inv = 1.f / fmaxf(sqrtf(ss), 1e-12f);
        if (lane == 0) invk[k] = inv;
        gss += ss * inv * inv;
    }
    if (lane == 0) wss[wave] = gss;
    __syncthreads();
    if (threadIdx.x == 0) {
        float g = wss[0] + wss[1] + wss[2] + wss[3];
        ginv_s = 1.f / fmaxf(sqrtf(g), 1e-12f);
    }
    __syncthreads();
    const float gi = ginv_s;
    for (int k = wave; k < Kc; k += 4) {
        const float a = asum[b * Kc + k];
        const float* pp = part + ((size_t)b * Kc + k) * Cc;
        const float* cp = centers + (size_t)k * Cc;
        const float scl = invk[k] * gi;
        float* op = out + ((size_t)b * Kc + k) * Cc;
#pragma unroll
        for (int cpass = 0; cpass < 8; ++cpass) {
            int c = cpass * 64 + lane;
            float v = pp[c] + pp[c + G] + pp[c + 2 * G] + pp[c + 3 * G] - a * cp[c];
            op[c] = v * scl;
        }
    }
}

extern "C" void kernel_launch(void* const* d_in, const int* in_sizes, int n_in,
                              void* d_out, int out_size, void* d_ws, size_t ws_size,
                              hipStream_t stream) {
    (void)in_sizes; (void)n_in; (void)out_size; (void)ws_size;
    const float* x       = (const float*)d_in[0];
    const float* centers = (const float*)d_in[1];
    const float* share_w = (const float*)d_in[2];
    const float* share_b = (const float*)d_in[3];
    const float* Uz      = (const float*)d_in[4];
    const float* Ur      = (const float*)d_in[5];
    const float* Uh      = (const float*)d_in[6];
    float* out = (float*)d_out;
    float* ws  = (float*)d_ws;

    float* wxb    = ws;                      // [T][B][K][S], reused later as part
    float* part   = ws;                      // alias (wxb dead after GRU)
    float* assign = ws + (size_t)TBKS;       // [T][B][K][S]
    float* zb     = assign + (size_t)TBKS;   // [B][K][S]
    float* rh     = zb + (size_t)BKS;
    float* h0     = rh + (size_t)BKS;
    float* wt     = h0 + (size_t)BKS;        // [C][K]
    float* asum   = wt + (size_t)Kc * Cc;    // [B][K]

    hipMemsetAsync(h0, 0, (size_t)BKS * sizeof(float), stream);
    k_transpose_w<<<dim3((Kc * Cc + 255) / 256), 256, 0, stream>>>(share_w, wt);
    k_conv1x1<<<dim3(784), 256, 0, stream>>>(x, wt, share_b, wxb);
    for (int t = 0; t < Tc; ++t) {
        const float* hp  = (t == 0) ? h0 : (assign + (size_t)(t - 1) * BKS);
        const float* wxt = wxb + (size_t)t * BKS;
        k_gru_gates<<<dim3(16, 16), 256, 0, stream>>>(hp, wxt, Uz, Ur, zb, rh);
        k_gru_out<<<dim3(16, 16), 256, 0, stream>>>(rh, hp, wxt, Uh, zb, assign + (size_t)t * BKS);
    }
    k_asum<<<dim3(Bc * Kc), 64, 0, stream>>>(assign, asum);
    k_einsum<<<dim3(4, 4, Bc), 256, 0, stream>>>(x, assign, part);
    k_finalize<<<dim3(Bc), 256, 0, stream>>>(part, asum, centers, out);
}

// Round 2
// 960.969 us; speedup vs baseline: 1.1901x; 1.1901x over previous
//
#include <hip/hip_runtime.h>

#define Bc 16
#define Tc 16
#define Cc 512
#define Kc 64
#define Sc 196
#define BKS (Bc*Kc*Sc)      // 200704
#define TBKS (Tc*BKS)       // 3211264

#define GPLANE 288                    // 18 rows * 16 cols per plane
#define GP_TOT (16 + 64*GPLANE + 16)  // 18464 floats incl guards

__device__ __forceinline__ float sigmoid_f(float x) { return 1.f / (1.f + __expf(-x)); }
__device__ __forceinline__ float tanh_f(float x) { return 1.f - 2.f / (__expf(2.f * x) + 1.f); }

// ---------------- transpose share_w: wt[c][k] = w[k][c] ----------------
__global__ __launch_bounds__(256) void k_transpose_w(const float* __restrict__ w, float* __restrict__ wt) {
    int idx = blockIdx.x * 256 + threadIdx.x;
    if (idx < Kc * Cc) {
        int k = idx & 63, c = idx >> 6;
        wt[idx] = w[k * Cc + c];
    }
}

// ---------------- conv1x1: wxb[t][b][k][s] = sum_c W[k][c] X[n][c][s] + bias[k] ----------------
__global__ __launch_bounds__(256) void k_conv1x1(const float* __restrict__ x, const float* __restrict__ wt,
                                                 const float* __restrict__ bias, float* __restrict__ wxb) {
    __shared__ float Ws[32][64];
    __shared__ float Xs[32][64];
    const int tid = threadIdx.x;
    const int gs0 = blockIdx.x * 64;
    const int kt = tid >> 4;
    const int sg = tid & 15;
    const int sr = tid >> 3;
    const int scol0 = (tid & 7) * 8;

    int nj[8], sj[8];
#pragma unroll
    for (int j = 0; j < 8; ++j) {
        int gs = gs0 + scol0 + j;
        nj[j] = gs / Sc;
        sj[j] = gs - nj[j] * Sc;
    }
    float acc[4][4] = {};
    for (int c0 = 0; c0 < Cc; c0 += 32) {
        __syncthreads();
        {
            const float* wp = wt + (size_t)(c0 + sr) * Kc + scol0;
            float4 a = *(const float4*)wp;
            float4 b = *(const float4*)(wp + 4);
            *(float4*)&Ws[sr][scol0] = a;
            *(float4*)&Ws[sr][scol0 + 4] = b;
        }
#pragma unroll
        for (int j = 0; j < 8; ++j) {
            Xs[sr][scol0 + j] = x[((size_t)nj[j] * Cc + c0 + sr) * Sc + sj[j]];
        }
        __syncthreads();
#pragma unroll
        for (int cc = 0; cc < 32; ++cc) {
            float4 wv = *(const float4*)&Ws[cc][kt * 4];
            float4 xv = *(const float4*)&Xs[cc][sg * 4];
            acc[0][0] += wv.x * xv.x; acc[0][1] += wv.x * xv.y; acc[0][2] += wv.x * xv.z; acc[0][3] += wv.x * xv.w;
            acc[1][0] += wv.y * xv.x; acc[1][1] += wv.y * xv.y; acc[1][2] += wv.y * xv.z; acc[1][3] += wv.y * xv.w;
            acc[2][0] += wv.z * xv.x; acc[2][1] += wv.z * xv.y; acc[2][2] += wv.z * xv.z; acc[2][3] += wv.z * xv.w;
            acc[3][0] += wv.w * xv.x; acc[3][1] += wv.w * xv.y; acc[3][2] += wv.w * xv.z; acc[3][3] += wv.w * xv.w;
        }
    }
#pragma unroll
    for (int i = 0; i < 4; ++i) {
        int k = kt * 4 + i;
        float bv = bias[k];
#pragma unroll
        for (int j = 0; j < 4; ++j) {
            int gs = gs0 + sg * 4 + j;
            int n = gs / Sc, s = gs - (gs / Sc) * Sc;
            int t = n & 15, b = n >> 4;
            wxb[(((size_t)t * Bc + b) * Kc + k) * Sc + s] = acc[i][j] + bv;
        }
    }
}

// ---------------- GRU gates: padded-plane LDS conv, 8 waves = 4 k_out x 2 ki-halves ----------------
__global__ __launch_bounds__(512) void k_gru_gates(const float* __restrict__ hprev,
        const float* __restrict__ wxb_t, const float* __restrict__ Uz, const float* __restrict__ Ur,
        float* __restrict__ zb, float* __restrict__ rh) {
    extern __shared__ float lds[];
    float* P = lds + 16;
    float* red = lds + GP_TOT;   // [4][64][8]
    const int b = blockIdx.y;
    const int k0 = blockIdx.x * 4;
    const int tid = threadIdx.x;

    for (int i = tid; i < GP_TOT; i += 512) lds[i] = 0.f;
    __syncthreads();
    {
        const float* hb = hprev + (size_t)b * (Kc * Sc);
        for (int i = tid; i < Kc * Sc; i += 512) {
            int kk = i / Sc, s = i - kk * Sc;
            int y = s / 14, x = s - y * 14;
            P[kk * GPLANE + (y + 2) * 16 + (x + 1)] = hb[i];
        }
    }
    __syncthreads();

    const int wave = tid >> 6, lane = tid & 63;
    const int k = __builtin_amdgcn_readfirstlane(k0 + (wave & 3));
    const int kih = __builtin_amdgcn_readfirstlane(wave >> 2);
    const float* uzp = Uz + (size_t)k * 576 + (size_t)kih * 288;
    const float* urp = Ur + (size_t)k * 576 + (size_t)kih * 288;
    const int yp = lane >> 2;
    const int xq = (lane & 3) * 4;
    float az[4] = {}, ar[4] = {};
    const float* Pr = P + kih * 32 * GPLANE + yp * 16 + xq;
#pragma unroll 2
    for (int ki = 0; ki < 32; ++ki) {
        float uz[9], ur[9];
#pragma unroll
        for (int q = 0; q < 9; ++q) { uz[q] = uzp[ki * 9 + q]; ur[q] = urp[ki * 9 + q]; }
        const float* pp = Pr + ki * GPLANE;
#pragma unroll
        for (int dyt = 0; dyt < 3; ++dyt) {
            const float* row = pp + dyt * 16;
            float4 m = *(const float4*)row;
            float e0 = row[-1], e4 = row[4];
            float cz0 = uz[3*dyt], cz1 = uz[3*dyt+1], cz2 = uz[3*dyt+2];
            float cr0 = ur[3*dyt], cr1 = ur[3*dyt+1], cr2 = ur[3*dyt+2];
            az[0] += cz0*e0  + cz1*m.x + cz2*m.y;
            az[1] += cz0*m.x + cz1*m.y + cz2*m.z;
            az[2] += cz0*m.y + cz1*m.z + cz2*m.w;
            az[3] += cz0*m.z + cz1*m.w + cz2*e4;
            ar[0] += cr0*e0  + cr1*m.x + cr2*m.y;
            ar[1] += cr0*m.x + cr1*m.y + cr2*m.z;
            ar[2] += cr0*m.y + cr1*m.z + cr2*m.w;
            ar[3] += cr0*m.z + cr1*m.w + cr2*e4;
        }
    }
    if (wave >= 4) {
        float* rp = red + ((size_t)(wave - 4) * 64 + lane) * 8;
        *(float4*)rp = make_float4(az[0], az[1], az[2], az[3]);
        *(float4*)(rp + 4) = make_float4(ar[0], ar[1], ar[2], ar[3]);
    }
    __syncthreads();
    if (wave < 4) {
        const float* rp = red + ((size_t)wave * 64 + lane) * 8;
        float4 a = *(const float4*)rp;
        float4 c = *(const float4*)(rp + 4);
        az[0] += a.x; az[1] += a.y; az[2] += a.z; az[3] += a.w;
        ar[0] += c.x; ar[1] += c.y; ar[2] += c.z; ar[3] += c.w;
        const size_t base = ((size_t)b * Kc + k) * Sc;
#pragma unroll
        for (int j = 0; j < 4; ++j) {
            int xp = xq + j;
            if (yp >= 1 && yp <= 14 && xp >= 1 && xp <= 14) {
                int s = (yp - 1) * 14 + (xp - 1);
                float pre = wxb_t[base + s];
                float zv = sigmoid_f(pre + az[j]);
                float rv = sigmoid_f(pre + ar[j]);
                float hv = P[k * GPLANE + (yp + 1) * 16 + xp];
                zb[base + s] = zv;
                rh[base + s] = rv * hv;
            }
        }
    }
}

// ---------------- GRU out: hh = tanh(wxb + conv(rh,Uh)); h = (1-z)*hh + z*hprev ----------------
__global__ __launch_bounds__(512) void k_gru_out(const float* __restrict__ rhin, const float* __restrict__ hprev,
        const float* __restrict__ wxb_t, const float* __restrict__ Uh, const float* __restrict__ zb,
        float* __restrict__ hout) {
    extern __shared__ float lds[];
    float* P = lds + 16;
    float* red = lds + GP_TOT;   // [4][64][4]
    const int b = blockIdx.y;
    const int k0 = blockIdx.x * 4;
    const int tid = threadIdx.x;

    for (int i = tid; i < GP_TOT; i += 512) lds[i] = 0.f;
    __syncthreads();
    {
        const float* hb = rhin + (size_t)b * (Kc * Sc);
        for (int i = tid; i < Kc * Sc; i += 512) {
            int kk = i / Sc, s = i - kk * Sc;
            int y = s / 14, x = s - y * 14;
            P[kk * GPLANE + (y + 2) * 16 + (x + 1)] = hb[i];
        }
    }
    __syncthreads();

    const int wave = tid >> 6, lane = tid & 63;
    const int k = __builtin_amdgcn_readfirstlane(k0 + (wave & 3));
    const int kih = __builtin_amdgcn_readfirstlane(wave >> 2);
    const float* uhp = Uh + (size_t)k * 576 + (size_t)kih * 288;
    const int yp = lane >> 2;
    const int xq = (lane & 3) * 4;
    float ah[4] = {};
    const float* Pr = P + kih * 32 * GPLANE + yp * 16 + xq;
#pragma unroll 2
    for (int ki = 0; ki < 32; ++ki) {
        float uh[9];
#pragma unroll
        for (int q = 0; q < 9; ++q) uh[q] = uhp[ki * 9 + q];
        const float* pp = Pr + ki * GPLANE;
#pragma unroll
        for (int dyt = 0; dyt < 3; ++dyt) {
            const float* row = pp + dyt * 16;
            float4 m = *(const float4*)row;
            float e0 = row[-1], e4 = row[4];
            float c0 = uh[3*dyt], c1 = uh[3*dyt+1], c2 = uh[3*dyt+2];
            ah[0] += c0*e0  + c1*m.x + c2*m.y;
            ah[1] += c0*m.x + c1*m.y + c2*m.z;
            ah[2] += c0*m.y + c1*m.z + c2*m.w;
            ah[3] += c0*m.z + c1*m.w + c2*e4;
        }
    }
    if (wave >= 4) {
        float* rp = red + ((size_t)(wave - 4) * 64 + lane) * 4;
        *(float4*)rp = make_float4(ah[0], ah[1], ah[2], ah[3]);
    }
    __syncthreads();
    if (wave < 4) {
        const float* rp = red + ((size_t)wave * 64 + lane) * 4;
        float4 a = *(const float4*)rp;
        ah[0] += a.x; ah[1] += a.y; ah[2] += a.z; ah[3] += a.w;
        const size_t base = ((size_t)b * Kc + k) * Sc;
#pragma unroll
        for (int j = 0; j < 4; ++j) {
            int xp = xq + j;
            if (yp >= 1 && yp <= 14 && xp >= 1 && xp <= 14) {
                int s = (yp - 1) * 14 + (xp - 1);
                float pre = wxb_t[base + s];
                float zv = zb[base + s];
                float hp = hprev[base + s];
                float hh = tanh_f(pre + ah[j]);
                hout[base + s] = (1.f - zv) * hh + zv * hp;
            }
        }
    }
}

// ---------------- asum_tot[b][k] = sum_{t,s} assign ----------------
__global__ __launch_bounds__(64) void k_asum(const float* __restrict__ assign, float* __restrict__ asum) {
    const int bk = blockIdx.x;
    const int b = bk >> 6, k = bk & 63;
    float s = 0.f;
    for (int i = threadIdx.x; i < Tc * Sc; i += 64) {
        int t = i / Sc, sp = i - t * Sc;
        s += assign[(((size_t)t * Bc + b) * Kc + k) * Sc + sp];
    }
#pragma unroll
    for (int o = 1; o < 64; o <<= 1) s += __shfl_xor(s, o);
    if (threadIdx.x == 0) asum[bk] = s;
}

// ---------------- einsum partials: transposed LDS tiles, float4 inner reads ----------------
__global__ __launch_bounds__(256) void k_einsum(const float* __restrict__ x, const float* __restrict__ assign,
                                                float* __restrict__ part) {
    extern __shared__ float lds[];
    float* As = lds;               // [196][68]
    float* Xs = lds + 196 * 68;    // [28][132]
    const int ct = blockIdx.x, tg = blockIdx.y, b = blockIdx.z;
    const int tid = threadIdx.x;
    const int kt = tid >> 4;       // k = kt*4 + i
    const int cg = tid & 15;       // c = ct*128 + cg*8 + j
    float acc[4][8] = {};
    for (int ti = 0; ti < 4; ++ti) {
        const int t = tg * 4 + ti;
        const int n = b * Tc + t;
        __syncthreads();
        {
            const float* ap = assign + ((size_t)t * Bc + b) * (Kc * Sc);
            for (int i = tid; i < Kc * Sc; i += 256) {
                int kk = i / Sc, s = i - kk * Sc;
                As[s * 68 + kk] = ap[i];
            }
        }
        for (int sc = 0; sc < 7; ++sc) {
            const int sb = sc * 28;
            __syncthreads();
            {
                const int r = tid >> 1, half = tid & 1;
                const float* xp = x + ((size_t)n * Cc + ct * 128 + r) * Sc + sb + half * 14;
#pragma unroll
                for (int j = 0; j < 14; ++j) Xs[(half * 14 + j) * 132 + r] = xp[j];
            }
            __syncthreads();
#pragma unroll 4
            for (int s = 0; s < 28; ++s) {
                float4 av = *(const float4*)&As[(sb + s) * 68 + kt * 4];
                float4 x0 = *(const float4*)&Xs[s * 132 + cg * 8];
                float4 x1 = *(const float4*)&Xs[s * 132 + cg * 8 + 4];
                acc[0][0] += av.x * x0.x; acc[0][1] += av.x * x0.y; acc[0][2] += av.x * x0.z; acc[0][3] += av.x * x0.w;
                acc[0][4] += av.x * x1.x; acc[0][5] += av.x * x1.y; acc[0][6] += av.x * x1.z; acc[0][7] += av.x * x1.w;
                acc[1][0] += av.y * x0.x; acc[1][1] += av.y * x0.y; acc[1][2] += av.y * x0.z; acc[1][3] += av.y * x0.w;
                acc[1][4] += av.y * x1.x; acc[1][5] += av.y * x1.y; acc[1][6] += av.y * x1.z; acc[1][7] += av.y * x1.w;
                acc[2][0] += av.z * x0.x; acc[2][1] += av.z * x0.y; acc[2][2] += av.z * x0.z; acc[2][3] += av.z * x0.w;
                acc[2][4] += av.z * x1.x; acc[2][5] += av.z * x1.y; acc[2][6] += av.z * x1.z; acc[2][7] += av.z * x1.w;
                acc[3][0] += av.w * x0.x; acc[3][1] += av.w * x0.y; acc[3][2] += av.w * x0.z; acc[3][3] += av.w * x0.w;
                acc[3][4] += av.w * x1.x; acc[3][5] += av.w * x1.y; acc[3][6] += av.w * x1.z; acc[3][7] += av.w * x1.w;
            }
        }
    }
#pragma unroll
    for (int i = 0; i < 4; ++i) {
        int k = kt * 4 + i;
        float* op = part + (((size_t)tg * Bc + b) * Kc + k) * Cc + ct * 128 + cg * 8;
        *(float4*)op = make_float4(acc[i][0], acc[i][1], acc[i][2], acc[i][3]);
        *(float4*)(op + 4) = make_float4(acc[i][4], acc[i][5], acc[i][6], acc[i][7]);
    }
}

// ---------------- finalize ----------------
__global__ __launch_bounds__(256) void k_finalize(const float* __restrict__ part, const float* __restrict__ asum,
        const float* __restrict__ centers, float* __restrict__ out) {
    __shared__ float invk[Kc];
    __shared__ float wss[4];
    __shared__ float ginv_s;
    const int b = blockIdx.x;
    const int wave = threadIdx.x >> 6, lane = threadIdx.x & 63;
    const size_t G = (size_t)Bc * Kc * Cc;
    float gss = 0.f;
    for (int k = wave; k < Kc; k += 4) {
        const float a = asum[b * Kc + k];
        const float* pp = part + ((size_t)b * Kc + k) * Cc;
        const float* cp = centers + (size_t)k * Cc;
        float ss = 0.f;
#pragma unroll
        for (int cpass = 0; cpass < 8; ++cpass) {
            int c = cpass * 64 + lane;
            float v = pp[c] + pp[c + G] + pp[c + 2 * G] + pp[c + 3 * G] - a * cp[c];
            ss += v * v;
        }
#pragma unroll
        for (int o = 1; o < 64; o <<= 1) ss += __shfl_xor(ss, o);
        float inv = 1.f / fmaxf(sqrtf(ss), 1e-12f);
        if (lane == 0) invk[k] = inv;
        gss += ss * inv * inv;
    }
    if (lane == 0) wss[wave] = gss;
    __syncthreads();
    if (threadIdx.x == 0) {
        float g = wss[0] + wss[1] + wss[2] + wss[3];
        ginv_s = 1.f / fmaxf(sqrtf(g), 1e-12f);
    }
    __syncthreads();
    const float gi = ginv_s;
    for (int k = wave; k < Kc; k += 4) {
        const float a = asum[b * Kc + k];
        const float* pp = part + ((size_t)b * Kc + k) * Cc;
        const float* cp = centers + (size_t)k * Cc;
        const float scl = invk[k] * gi;
        float* op = out + ((size_t)b * Kc + k) * Cc;
#pragma unroll
        for (int cpass = 0; cpass < 8; ++cpass) {
            int c = cpass * 64 + lane;
            float v = pp[c] + pp[c + G] + pp[c + 2 * G] + pp[c + 3 * G] - a * cp[c];
            op[c] = v * scl;
        }
    }
}

extern "C" void kernel_launch(void* const* d_in, const int* in_sizes, int n_in,
                              void* d_out, int out_size, void* d_ws, size_t ws_size,
                              hipStream_t stream) {
    (void)in_sizes; (void)n_in; (void)out_size; (void)ws_size;
    const float* x       = (const float*)d_in[0];
    const float* centers = (const float*)d_in[1];
    const float* share_w = (const float*)d_in[2];
    const float* share_b = (const float*)d_in[3];
    const float* Uz      = (const float*)d_in[4];
    const float* Ur      = (const float*)d_in[5];
    const float* Uh      = (const float*)d_in[6];
    float* out = (float*)d_out;
    float* ws  = (float*)d_ws;

    float* wxb    = ws;                      // [T][B][K][S], reused later as part
    float* part   = ws;                      // alias (wxb dead after GRU)
    float* assign = ws + (size_t)TBKS;       // [T][B][K][S]
    float* zb     = assign + (size_t)TBKS;   // [B][K][S]
    float* rh     = zb + (size_t)BKS;
    float* h0     = rh + (size_t)BKS;
    float* wt     = h0 + (size_t)BKS;        // [C][K]
    float* asum   = wt + (size_t)Kc * Cc;    // [B][K]

    const size_t gates_lds = (size_t)(GP_TOT + 4 * 64 * 8) * 4;
    const size_t outk_lds  = (size_t)(GP_TOT + 4 * 64 * 4) * 4;
    const size_t ein_lds   = (size_t)(196 * 68 + 28 * 132) * 4;

    hipMemsetAsync(h0, 0, (size_t)BKS * sizeof(float), stream);
    k_transpose_w<<<dim3((Kc * Cc + 255) / 256), 256, 0, stream>>>(share_w, wt);
    k_conv1x1<<<dim3(784), 256, 0, stream>>>(x, wt, share_b, wxb);
    for (int t = 0; t < Tc; ++t) {
        const float* hp  = (t == 0) ? h0 : (assign + (size_t)(t - 1) * BKS);
        const float* wxt = wxb + (size_t)t * BKS;
        k_gru_gates<<<dim3(16, 16), 512, gates_lds, stream>>>(hp, wxt, Uz, Ur, zb, rh);
        k_gru_out<<<dim3(16, 16), 512, outk_lds, stream>>>(rh, hp, wxt, Uh, zb, assign + (size_t)t * BKS);
    }
    k_asum<<<dim3(Bc * Kc), 64, 0, stream>>>(assign, asum);
    k_einsum<<<dim3(4, 4, Bc), 256, ein_lds, stream>>>(x, assign, part);
    k_finalize<<<dim3(Bc), 256, 0, stream>>>(part, asum, centers, out);
}

// Round 3
// 672.760 us; speedup vs baseline: 1.7000x; 1.4284x over previous
//
#include <hip/hip_runtime.h>

#define Bc 16
#define Tc 16
#define Cc 512
#define Kc 64
#define Sc 196
#define BKS (Bc*Kc*Sc)      // 200704
#define TBKS (Tc*BKS)       // 3211264

#define GPLANE 288                    // 18 rows * 16 cols per plane
#define GP_TOT (16 + 64*GPLANE + 16)  // 18464 floats incl guards

__device__ __forceinline__ float sigmoid_f(float x) { return 1.f / (1.f + __expf(-x)); }
__device__ __forceinline__ float tanh_f(float x) { return 1.f - 2.f / (__expf(2.f * x) + 1.f); }

// ---------------- transpose share_w: wt[c][k] = w[k][c] ----------------
__global__ __launch_bounds__(256) void k_transpose_w(const float* __restrict__ w, float* __restrict__ wt) {
    int idx = blockIdx.x * 256 + threadIdx.x;
    if (idx < Kc * Cc) {
        int k = idx & 63, c = idx >> 6;
        wt[idx] = w[k * Cc + c];
    }
}

// ---------------- conv1x1: wxb[t][b][k][s] = sum_c W[k][c] X[n][c][s] + bias[k] ----------------
__global__ __launch_bounds__(256) void k_conv1x1(const float* __restrict__ x, const float* __restrict__ wt,
                                                 const float* __restrict__ bias, float* __restrict__ wxb) {
    __shared__ float Ws[32][64];
    __shared__ float Xs[32][64];
    const int tid = threadIdx.x;
    const int gs0 = blockIdx.x * 64;
    const int kt = tid >> 4;          // k = kt*4 + i
    const int sg = tid & 15;          // gs col = sg*4 + j
    const int sr = tid >> 3;
    const int scol0 = (tid & 7) * 8;

    float acc[4][4] = {};
    for (int c0 = 0; c0 < Cc; c0 += 32) {
        __syncthreads();
        {
            const float* wp = wt + (size_t)(c0 + sr) * Kc + scol0;
            float4 a = *(const float4*)wp;
            float4 b = *(const float4*)(wp + 4);
            *(float4*)&Ws[sr][scol0] = a;
            *(float4*)&Ws[sr][scol0 + 4] = b;
        }
        // coalesced X staging: consecutive tid -> consecutive gs (contiguous global, contiguous LDS)
        for (int ii = tid; ii < 2048; ii += 256) {
            int c = ii >> 6, go = ii & 63;
            int gs = gs0 + go;
            int n = gs / Sc, s = gs - n * Sc;
            Xs[c][go] = x[((size_t)n * Cc + c0 + c) * Sc + s];
        }
        __syncthreads();
#pragma unroll
        for (int cc = 0; cc < 32; ++cc) {
            float4 wv = *(const float4*)&Ws[cc][kt * 4];
            float4 xv = *(const float4*)&Xs[cc][sg * 4];
            acc[0][0] += wv.x * xv.x; acc[0][1] += wv.x * xv.y; acc[0][2] += wv.x * xv.z; acc[0][3] += wv.x * xv.w;
            acc[1][0] += wv.y * xv.x; acc[1][1] += wv.y * xv.y; acc[1][2] += wv.y * xv.z; acc[1][3] += wv.y * xv.w;
            acc[2][0] += wv.z * xv.x; acc[2][1] += wv.z * xv.y; acc[2][2] += wv.z * xv.z; acc[2][3] += wv.z * xv.w;
            acc[3][0] += wv.w * xv.x; acc[3][1] += wv.w * xv.y; acc[3][2] += wv.w * xv.z; acc[3][3] += wv.w * xv.w;
        }
    }
#pragma unroll
    for (int i = 0; i < 4; ++i) {
        int k = kt * 4 + i;
        float bv = bias[k];
#pragma unroll
        for (int j = 0; j < 4; ++j) {
            int gs = gs0 + sg * 4 + j;
            int n = gs / Sc, s = gs - (gs / Sc) * Sc;
            int t = n & 15, b = n >> 4;
            wxb[(((size_t)t * Bc + b) * Kc + k) * Sc + s] = acc[i][j] + bv;
        }
    }
}

// ---------------- GRU gates: wave = 4 k_out x ki-eighth; lane-major reduce ----------------
// grid (16 b, 16 ktile), block 512. red = [8 waves][32 idx][64 lane]
__global__ __launch_bounds__(512) void k_gru_gates(const float* __restrict__ hprev,
        const float* __restrict__ wxb_t, const float* __restrict__ Uz, const float* __restrict__ Ur,
        float* __restrict__ zb, float* __restrict__ rh) {
    extern __shared__ float lds[];
    float* P = lds + 16;
    float* red = lds + GP_TOT;
    const int b = blockIdx.x;
    const int k0 = blockIdx.y * 4;
    const int tid = threadIdx.x;

    for (int i = tid; i < GP_TOT; i += 512) lds[i] = 0.f;
    __syncthreads();
    {
        const float* hb = hprev + (size_t)b * (Kc * Sc);
        for (int i = tid; i < Kc * Sc; i += 512) {
            int kk = i / Sc, s = i - kk * Sc;
            int y = s / 14, xx = s - y * 14;
            P[kk * GPLANE + (y + 2) * 16 + xx + 1] = hb[i];
        }
    }
    __syncthreads();

    const int wave = tid >> 6, lane = tid & 63;
    const int kiw = __builtin_amdgcn_readfirstlane(wave << 3);   // ki base
    const int yp = lane >> 2, xq = (lane & 3) << 2;
    const float* uz0 = Uz + (size_t)k0 * 576 + (size_t)kiw * 9;
    const float* ur0 = Ur + (size_t)k0 * 576 + (size_t)kiw * 9;
    float az[4][4] = {}, ar[4][4] = {};
    const float* Pw = P + (size_t)kiw * GPLANE + yp * 16 + xq;
#pragma unroll 2
    for (int ki = 0; ki < 8; ++ki) {
        const float* pk = Pw + ki * GPLANE;
#pragma unroll
        for (int dy = 0; dy < 3; ++dy) {
            const float* row = pk + dy * 16;
            float4 m = *(const float4*)row;
            float e0 = row[-1], e4 = row[4];
#pragma unroll
            for (int r = 0; r < 4; ++r) {
                const float* wz = uz0 + r * 576 + ki * 9 + dy * 3;
                float c0 = wz[0], c1 = wz[1], c2 = wz[2];
                az[r][0] += c0*e0  + c1*m.x + c2*m.y;
                az[r][1] += c0*m.x + c1*m.y + c2*m.z;
                az[r][2] += c0*m.y + c1*m.z + c2*m.w;
                az[r][3] += c0*m.z + c1*m.w + c2*e4;
                const float* wr = ur0 + r * 576 + ki * 9 + dy * 3;
                float d0 = wr[0], d1 = wr[1], d2 = wr[2];
                ar[r][0] += d0*e0  + d1*m.x + d2*m.y;
                ar[r][1] += d0*m.x + d1*m.y + d2*m.z;
                ar[r][2] += d0*m.y + d1*m.z + d2*m.w;
                ar[r][3] += d0*m.z + d1*m.w + d2*e4;
            }
        }
    }
    {   // conflict-free partial write: idx = r*8 + g*4 + j, lane-major
        float* rp = red + (size_t)wave * 2048 + lane;
#pragma unroll
        for (int r = 0; r < 4; ++r)
#pragma unroll
            for (int j = 0; j < 4; ++j) {
                rp[(size_t)(r * 8 + j) * 64] = az[r][j];
                rp[(size_t)(r * 8 + 4 + j) * 64] = ar[r][j];
            }
    }
    __syncthreads();
    {   // epilogue: thread owns (g = wave>>2, j = wave&3), 4 values r=0..3
        const int g = wave >> 2, j = wave & 3;
        const int yq = lane >> 2;
        const int xb = ((lane & 3) << 2) + j;
        float v[4];
#pragma unroll
        for (int r = 0; r < 4; ++r) {
            const int idx = r * 8 + g * 4 + j;
            float s0 = 0.f;
#pragma unroll
            for (int w = 0; w < 8; ++w) s0 += red[(size_t)(w * 32 + idx) * 64 + lane];
            v[r] = s0;
        }
        if (yq >= 1 && yq <= 14 && xb >= 1 && xb <= 14) {
            const int s = (yq - 1) * 14 + (xb - 1);
#pragma unroll
            for (int r = 0; r < 4; ++r) {
                const size_t base = ((size_t)b * Kc + k0 + r) * Sc + s;
                float pre = wxb_t[base];
                if (g == 0) {
                    zb[base] = sigmoid_f(pre + v[r]);
                } else {
                    float hv = P[(size_t)(k0 + r) * GPLANE + (yq + 1) * 16 + xb];
                    rh[base] = sigmoid_f(pre + v[r]) * hv;
                }
            }
        }
    }
}

// ---------------- GRU out: hh = tanh(wxb + conv(rh,Uh)); h = (1-z)*hh + z*hprev ----------------
__global__ __launch_bounds__(512) void k_gru_out(const float* __restrict__ rhin, const float* __restrict__ hprev,
        const float* __restrict__ wxb_t, const float* __restrict__ Uh, const float* __restrict__ zb,
        float* __restrict__ hout) {
    extern __shared__ float lds[];
    float* P = lds + 16;
    float* red = lds + GP_TOT;    // [8][16][64]
    const int b = blockIdx.x;
    const int k0 = blockIdx.y * 4;
    const int tid = threadIdx.x;

    for (int i = tid; i < GP_TOT; i += 512) lds[i] = 0.f;
    __syncthreads();
    {
        const float* hb = rhin + (size_t)b * (Kc * Sc);
        for (int i = tid; i < Kc * Sc; i += 512) {
            int kk = i / Sc, s = i - kk * Sc;
            int y = s / 14, xx = s - y * 14;
            P[kk * GPLANE + (y + 2) * 16 + xx + 1] = hb[i];
        }
    }
    __syncthreads();

    const int wave = tid >> 6, lane = tid & 63;
    const int kiw = __builtin_amdgcn_readfirstlane(wave << 3);
    const int yp = lane >> 2, xq = (lane & 3) << 2;
    const float* uh0 = Uh + (size_t)k0 * 576 + (size_t)kiw * 9;
    float ah[4][4] = {};
    const float* Pw = P + (size_t)kiw * GPLANE + yp * 16 + xq;
#pragma unroll 2
    for (int ki = 0; ki < 8; ++ki) {
        const float* pk = Pw + ki * GPLANE;
#pragma unroll
        for (int dy = 0; dy < 3; ++dy) {
            const float* row = pk + dy * 16;
            float4 m = *(const float4*)row;
            float e0 = row[-1], e4 = row[4];
#pragma unroll
            for (int r = 0; r < 4; ++r) {
                const float* wh = uh0 + r * 576 + ki * 9 + dy * 3;
                float c0 = wh[0], c1 = wh[1], c2 = wh[2];
                ah[r][0] += c0*e0  + c1*m.x + c2*m.y;
                ah[r][1] += c0*m.x + c1*m.y + c2*m.z;
                ah[r][2] += c0*m.y + c1*m.z + c2*m.w;
                ah[r][3] += c0*m.z + c1*m.w + c2*e4;
            }
        }
    }
    {
        float* rp = red + (size_t)wave * 1024 + lane;
#pragma unroll
        for (int r = 0; r < 4; ++r)
#pragma unroll
            for (int j = 0; j < 4; ++j)
                rp[(size_t)(r * 4 + j) * 64] = ah[r][j];
    }
    __syncthreads();
    {   // thread owns (j = wave&3, rr = wave>>2); values r = rr + 2m
        const int j = wave & 3, rr = wave >> 2;
        const int yq = lane >> 2;
        const int xb = ((lane & 3) << 2) + j;
        float v[2];
#pragma unroll
        for (int m = 0; m < 2; ++m) {
            const int idx = (rr + 2 * m) * 4 + j;
            float s0 = 0.f;
#pragma unroll
            for (int w = 0; w < 8; ++w) s0 += red[(size_t)(w * 16 + idx) * 64 + lane];
            v[m] = s0;
        }
        if (yq >= 1 && yq <= 14 && xb >= 1 && xb <= 14) {
            const int s = (yq - 1) * 14 + (xb - 1);
#pragma unroll
            for (int m = 0; m < 2; ++m) {
                const int r = rr + 2 * m;
                const size_t base = ((size_t)b * Kc + k0 + r) * Sc + s;
                float pre = wxb_t[base];
                float zv = zb[base];
                float hp = hprev[base];
                float hh = tanh_f(pre + v[m]);
                hout[base] = (1.f - zv) * hh + zv * hp;
            }
        }
    }
}

// ---------------- asum_tot[b][k] = sum_{t,s} assign ----------------
__global__ __launch_bounds__(64) void k_asum(const float* __restrict__ assign, float* __restrict__ asum) {
    const int bk = blockIdx.x;
    const int b = bk >> 6, k = bk & 63;
    float s = 0.f;
    for (int i = threadIdx.x; i < Tc * Sc; i += 64) {
        int t = i / Sc, sp = i - t * Sc;
        s += assign[(((size_t)t * Bc + b) * Kc + k) * Sc + sp];
    }
#pragma unroll
    for (int o = 1; o < 64; o <<= 1) s += __shfl_xor(s, o);
    if (threadIdx.x == 0) asum[bk] = s;
}

// ---------------- einsum: 512 thr, conflict-free Xs via register transpose, s-half split ----------------
// wave w: kq = w&3 (k-quarter), sh = w>>2 (s-half); lane: kh = lane>>5, c32 = lane&31
__global__ __launch_bounds__(512) void k_einsum(const float* __restrict__ x, const float* __restrict__ assign,
                                                float* __restrict__ part) {
    extern __shared__ float lds[];
    float* As = lds;                 // [196][68]  (reads are 2-addr broadcast)
    float* Xs = lds + 196 * 68;      // [28][132]  (reads 64-lane contiguous)
    const int ct = blockIdx.x, tg = blockIdx.y, b = blockIdx.z;
    const int tid = threadIdx.x;
    const int wave = tid >> 6, lane = tid & 63;
    const int kq = wave & 3, sh = wave >> 2;
    const int kh = lane >> 5, c32 = lane & 31;
    const int kbase = kq * 16 + kh * 8;
    float4 acc[8] = {};
    for (int ti = 0; ti < 4; ++ti) {
        const int t = tg * 4 + ti;
        const int n = b * Tc + t;
        __syncthreads();
        {
            const float* ap = assign + ((size_t)t * Bc + b) * (Kc * Sc);
            for (int i = tid; i < Kc * Sc; i += 512) {
                int kk = i / Sc, s = i - kk * Sc;
                As[(size_t)s * 68 + kk] = ap[i];
            }
        }
        for (int sc = 0; sc < 7; ++sc) {
            const int sb = sc * 28;
            __syncthreads();
            if (tid < 224) {   // 4x4 register transpose staging: conflict-free LDS writes
                const int sg = tid >> 5, cgi = tid & 31;
                const float* xp = x + ((size_t)n * Cc + ct * 128 + cgi * 4) * Sc + sb + sg * 4;
                float4 r0 = *(const float4*)xp;
                float4 r1 = *(const float4*)(xp + Sc);
                float4 r2 = *(const float4*)(xp + 2 * Sc);
                float4 r3 = *(const float4*)(xp + 3 * Sc);
                float* xd = Xs + (size_t)(sg * 4) * 132 + cgi * 4;
                *(float4*)(xd)       = make_float4(r0.x, r1.x, r2.x, r3.x);
                *(float4*)(xd + 132) = make_float4(r0.y, r1.y, r2.y, r3.y);
                *(float4*)(xd + 264) = make_float4(r0.z, r1.z, r2.z, r3.z);
                *(float4*)(xd + 396) = make_float4(r0.w, r1.w, r2.w, r3.w);
            }
            __syncthreads();
            const int s0 = sh * 14;
#pragma unroll 2
            for (int si = 0; si < 14; ++si) {
                const int sl = s0 + si;
                const float* ap = As + (size_t)(sb + sl) * 68 + kbase;
                float4 a0 = *(const float4*)ap;
                float4 a1 = *(const float4*)(ap + 4);
                float4 xv = *(const float4*)(Xs + (size_t)sl * 132 + c32 * 4);
                acc[0].x += a0.x * xv.x; acc[0].y += a0.x * xv.y; acc[0].z += a0.x * xv.z; acc[0].w += a0.x * xv.w;
                acc[1].x += a0.y * xv.x; acc[1].y += a0.y * xv.y; acc[1].z += a0.y * xv.z; acc[1].w += a0.y * xv.w;
                acc[2].x += a0.z * xv.x; acc[2].y += a0.z * xv.y; acc[2].z += a0.z * xv.z; acc[2].w += a0.z * xv.w;
                acc[3].x += a0.w * xv.x; acc[3].y += a0.w * xv.y; acc[3].z += a0.w * xv.z; acc[3].w += a0.w * xv.w;
                acc[4].x += a1.x * xv.x; acc[4].y += a1.x * xv.y; acc[4].z += a1.x * xv.z; acc[4].w += a1.x * xv.w;
                acc[5].x += a1.y * xv.x; acc[5].y += a1.y * xv.y; acc[5].z += a1.y * xv.z; acc[5].w += a1.y * xv.w;
                acc[6].x += a1.z * xv.x; acc[6].y += a1.z * xv.y; acc[6].z += a1.z * xv.z; acc[6].w += a1.z * xv.w;
                acc[7].x += a1.w * xv.x; acc[7].y += a1.w * xv.y; acc[7].z += a1.w * xv.z; acc[7].w += a1.w * xv.w;
            }
        }
    }
    __syncthreads();   // As dead; reuse as reduce buffer [4][32][64]
    if (sh == 1) {
        float* rp = As + (size_t)kq * 2048 + lane;
#pragma unroll
        for (int q = 0; q < 8; ++q) {
            rp[(size_t)(q * 4 + 0) * 64] = acc[q].x;
            rp[(size_t)(q * 4 + 1) * 64] = acc[q].y;
            rp[(size_t)(q * 4 + 2) * 64] = acc[q].z;
            rp[(size_t)(q * 4 + 3) * 64] = acc[q].w;
        }
    }
    __syncthreads();
    if (sh == 0) {
        const float* rp = As + (size_t)kq * 2048 + lane;
#pragma unroll
        for (int q = 0; q < 8; ++q) {
            acc[q].x += rp[(size_t)(q * 4 + 0) * 64];
            acc[q].y += rp[(size_t)(q * 4 + 1) * 64];
            acc[q].z += rp[(size_t)(q * 4 + 2) * 64];
            acc[q].w += rp[(size_t)(q * 4 + 3) * 64];
        }
#pragma unroll
        for (int q = 0; q < 8; ++q) {
            const int k = kbase + q;
            float* op = part + (((size_t)tg * Bc + b) * Kc + k) * Cc + ct * 128 + c32 * 4;
            *(float4*)op = acc[q];
        }
    }
}

// ---------------- finalize ----------------
__global__ __launch_bounds__(256) void k_finalize(const float* __restrict__ part, const float* __restrict__ asum,
        const float* __restrict__ centers, float* __restrict__ out) {
    __shared__ float invk[Kc];
    __shared__ float wss[4];
    __shared__ float ginv_s;
    const int b = blockIdx.x;
    const int wave = threadIdx.x >> 6, lane = threadIdx.x & 63;
    const size_t G = (size_t)Bc * Kc * Cc;
    float gss = 0.f;
    for (int k = wave; k < Kc; k += 4) {
        const float a = asum[b * Kc + k];
        const float* pp = part + ((size_t)b * Kc + k) * Cc;
        const float* cp = centers + (size_t)k * Cc;
        float ss = 0.f;
#pragma unroll
        for (int cpass = 0; cpass < 8; ++cpass) {
            int c = cpass * 64 + lane;
            float v = pp[c] + pp[c + G] + pp[c + 2 * G] + pp[c + 3 * G] - a * cp[c];
            ss += v * v;
        }
#pragma unroll
        for (int o = 1; o < 64; o <<= 1) ss += __shfl_xor(ss, o);
        float inv = 1.f / fmaxf(sqrtf(ss), 1e-12f);
        if (lane == 0) invk[k] = inv;
        gss += ss * inv * inv;
    }
    if (lane == 0) wss[wave] = gss;
    __syncthreads();
    if (threadIdx.x == 0) {
        float g = wss[0] + wss[1] + wss[2] + wss[3];
        ginv_s = 1.f / fmaxf(sqrtf(g), 1e-12f);
    }
    __syncthreads();
    const float gi = ginv_s;
    for (int k = wave; k < Kc; k += 4) {
        const float a = asum[b * Kc + k];
        const float* pp = part + ((size_t)b * Kc + k) * Cc;
        const float* cp = centers + (size_t)k * Cc;
        const float scl = invk[k] * gi;
        float* op = out + ((size_t)b * Kc + k) * Cc;
#pragma unroll
        for (int cpass = 0; cpass < 8; ++cpass) {
            int c = cpass * 64 + lane;
            float v = pp[c] + pp[c + G] + pp[c + 2 * G] + pp[c + 3 * G] - a * cp[c];
            op[c] = v * scl;
        }
    }
}

extern "C" void kernel_launch(void* const* d_in, const int* in_sizes, int n_in,
                              void* d_out, int out_size, void* d_ws, size_t ws_size,
                              hipStream_t stream) {
    (void)in_sizes; (void)n_in; (void)out_size; (void)ws_size;
    const float* x       = (const float*)d_in[0];
    const float* centers = (const float*)d_in[1];
    const float* share_w = (const float*)d_in[2];
    const float* share_b = (const float*)d_in[3];
    const float* Uz      = (const float*)d_in[4];
    const float* Ur      = (const float*)d_in[5];
    const float* Uh      = (const float*)d_in[6];
    float* out = (float*)d_out;
    float* ws  = (float*)d_ws;

    float* wxb    = ws;                      // [T][B][K][S], reused later as part
    float* part   = ws;                      // alias (wxb dead after GRU)
    float* assign = ws + (size_t)TBKS;       // [T][B][K][S]
    float* zb     = assign + (size_t)TBKS;   // [B][K][S]
    float* rh     = zb + (size_t)BKS;
    float* h0     = rh + (size_t)BKS;
    float* wt     = h0 + (size_t)BKS;        // [C][K]
    float* asum   = wt + (size_t)Kc * Cc;    // [B][K]

    const size_t gates_lds = (size_t)(GP_TOT + 8 * 32 * 64) * 4;   // 136.1 KB
    const size_t outk_lds  = (size_t)(GP_TOT + 8 * 16 * 64) * 4;   // 104.1 KB
    const size_t ein_lds   = (size_t)(196 * 68 + 28 * 132) * 4;    // 66.5 KB

    hipMemsetAsync(h0, 0, (size_t)BKS * sizeof(float), stream);
    k_transpose_w<<<dim3((Kc * Cc + 255) / 256), 256, 0, stream>>>(share_w, wt);
    k_conv1x1<<<dim3(784), 256, 0, stream>>>(x, wt, share_b, wxb);
    for (int t = 0; t < Tc; ++t) {
        const float* hp  = (t == 0) ? h0 : (assign + (size_t)(t - 1) * BKS);
        const float* wxt = wxb + (size_t)t * BKS;
        k_gru_gates<<<dim3(16, 16), 512, gates_lds, stream>>>(hp, wxt, Uz, Ur, zb, rh);
        k_gru_out<<<dim3(16, 16), 512, outk_lds, stream>>>(rh, hp, wxt, Uh, zb, assign + (size_t)t * BKS);
    }
    k_asum<<<dim3(Bc * Kc), 64, 0, stream>>>(assign, asum);
    k_einsum<<<dim3(4, 4, Bc), 512, ein_lds, stream>>>(x, assign, part);
    k_finalize<<<dim3(Bc), 256, 0, stream>>>(part, asum, centers, out);
}